// Round 1
// baseline (844.244 us; speedup 1.0000x reference)
//
#include <hip/hip_runtime.h>
#include <math.h>

namespace {
constexpr int B = 8, S = 2048, H = 128, NH = 4, HS = 32;
constexpr float EPS = 1e-8f;
constexpr float SCALE = 0.17677669529663687f;  // 1/sqrt(32)
constexpr int QT = 64, KT = 64;
constexpr int LDK = 36;    // padded row stride (floats) for 32-wide tiles; 144B = 16B-aligned rows
constexpr int LDSC = 65;   // score tile row stride
}

// ---------------- Kernel 1: 5 fused projections (Q,K,V from item; Qb,Kb from behavior) ----------
__global__ __launch_bounds__(256) void proj_kernel(
    const float* __restrict__ item, const float* __restrict__ beh,
    const float* __restrict__ Wq, const float* __restrict__ bq,
    const float* __restrict__ Wk, const float* __restrict__ bk,
    const float* __restrict__ Wv, const float* __restrict__ bv,
    const float* __restrict__ Wqb, const float* __restrict__ bqb,
    const float* __restrict__ Wkb, const float* __restrict__ bkb,
    float* __restrict__ Qo, float* __restrict__ Ko, float* __restrict__ Vo,
    float* __restrict__ Qbo, float* __restrict__ Kbo)
{
  __shared__ float xi[16 * H];
  __shared__ float xb[16 * H];
  const int t = threadIdx.x;
  const long r0 = (long)blockIdx.x * 16;
  {
    const float4* gi = (const float4*)(item + r0 * H);
    const float4* gb = (const float4*)(beh + r0 * H);
    float4* si = (float4*)xi;
    float4* sb = (float4*)xb;
    si[t] = gi[t]; si[t + 256] = gi[t + 256];
    sb[t] = gb[t]; sb[t + 256] = gb[t + 256];
  }
  __syncthreads();
  const int c = t & (H - 1);
  const int rr = t >> 7;           // 0/1: thread owns rows rr, rr+2, ..., rr+14
  const float* Ws[5] = {Wq, Wk, Wv, Wqb, Wkb};
  const float* bias[5] = {bq, bk, bv, bqb, bkb};
  float* dst[5] = {Qo, Ko, Vo, Qbo, Kbo};
  const int bb = (int)(r0 >> 11);  // r0/S
  const int h = c >> 5;
  const int d = c & 31;
  for (int p = 0; p < 5; ++p) {
    const float* W = Ws[p];
    const float* x = (p < 3) ? xi : xb;
    float acc[8];
    const float bz = bias[p][c];
#pragma unroll
    for (int i = 0; i < 8; ++i) acc[i] = bz;
    for (int k = 0; k < H; k += 4) {
      const float w0 = W[(k + 0) * H + c];
      const float w1 = W[(k + 1) * H + c];
      const float w2 = W[(k + 2) * H + c];
      const float w3 = W[(k + 3) * H + c];
#pragma unroll
      for (int i = 0; i < 8; ++i) {
        const float4 xv = *(const float4*)&x[(rr + 2 * i) * H + k];
        acc[i] += xv.x * w0 + xv.y * w1 + xv.z * w2 + xv.w * w3;
      }
    }
#pragma unroll
    for (int i = 0; i < 8; ++i) {
      const long r = r0 + rr + 2 * i;
      const long s = r & (S - 1);
      const long idx = (((long)bb * NH + h) * S + s) * HS + d;  // [B][NH][S][HS]
      dst[p][idx] = acc[i];
    }
  }
}

// ---------------- Kernel 2: flash attention with dual-score (QK^T + QbKb^T) ----------
__global__ __launch_bounds__(256) void attn_kernel(
    const float* __restrict__ Qg, const float* __restrict__ Kg, const float* __restrict__ Vg,
    const float* __restrict__ Qbg, const float* __restrict__ Kbg,
    const float* __restrict__ mask, float* __restrict__ attn_out)
{
  __shared__ float Qs[QT * LDK], Qbs[QT * LDK];
  __shared__ float Ks[KT * LDK], Kbs[KT * LDK], Vs[KT * LDK];
  __shared__ float Sc[QT * LDSC];
  __shared__ float mrow[QT], lrow[QT], arow[QT];

  const int t = threadIdx.x;
  const int bh = blockIdx.x;      // b*NH + h
  const int qt = blockIdx.y;      // q-tile
  const int b = bh >> 2;
  const int h = bh & (NH - 1);
  const int q0 = qt * QT;
  const long base = (long)bh * S * HS;

  {
    const float4* gq = (const float4*)(Qg + base + (long)q0 * HS);
    const float4* gqb = (const float4*)(Qbg + base + (long)q0 * HS);
#pragma unroll
    for (int u = 0; u < 2; ++u) {
      const int idx4 = t + u * 256;       // 0..511 float4s (64 rows x 8)
      const int row = idx4 >> 3;
      const int col = (idx4 & 7) * 4;
      *(float4*)&Qs[row * LDK + col] = gq[idx4];
      *(float4*)&Qbs[row * LDK + col] = gqb[idx4];
    }
  }
  if (t < QT) { mrow[t] = -INFINITY; lrow[t] = 0.f; }

  float O[2][4] = {};
  const int kg = t & 15;          // scores: k = kg + 16j
  const int qg = t >> 4;          // scores: q = qg + 16i
  const int dg = t & 7;           // pv: d = dg*4..+3
  const int qg2 = t >> 3;         // pv: q = qg2 + 32i
  const float* mg = mask + (long)b * S * S + (long)q0 * S;

  for (int kt = 0; kt < S / KT; ++kt) {
    const int k0 = kt * KT;
    __syncthreads();               // prev PV done before overwriting K/V/Sc
    {
      const float4* gk = (const float4*)(Kg + base + (long)k0 * HS);
      const float4* gkb = (const float4*)(Kbg + base + (long)k0 * HS);
      const float4* gv = (const float4*)(Vg + base + (long)k0 * HS);
#pragma unroll
      for (int u = 0; u < 2; ++u) {
        const int idx4 = t + u * 256;
        const int row = idx4 >> 3;
        const int col = (idx4 & 7) * 4;
        *(float4*)&Ks[row * LDK + col] = gk[idx4];
        *(float4*)&Kbs[row * LDK + col] = gkb[idx4];
        *(float4*)&Vs[row * LDK + col] = gv[idx4];
      }
    }
    __syncthreads();
    // ---- scores: 4q x 4k register tile per thread, float4 over d ----
    {
      float acc[4][4] = {};
      for (int dc = 0; dc < HS; dc += 4) {
        float4 qv[4], qbv[4], kv[4], kbv[4];
#pragma unroll
        for (int i = 0; i < 4; ++i) {
          qv[i]  = *(const float4*)&Qs[(qg + 16 * i) * LDK + dc];
          qbv[i] = *(const float4*)&Qbs[(qg + 16 * i) * LDK + dc];
          kv[i]  = *(const float4*)&Ks[(kg + 16 * i) * LDK + dc];
          kbv[i] = *(const float4*)&Kbs[(kg + 16 * i) * LDK + dc];
        }
#pragma unroll
        for (int i = 0; i < 4; ++i)
#pragma unroll
          for (int j = 0; j < 4; ++j) {
            acc[i][j] += qv[i].x * kv[j].x + qv[i].y * kv[j].y
                       + qv[i].z * kv[j].z + qv[i].w * kv[j].w
                       + qbv[i].x * kbv[j].x + qbv[i].y * kbv[j].y
                       + qbv[i].z * kbv[j].z + qbv[i].w * kbv[j].w;
          }
      }
#pragma unroll
      for (int i = 0; i < 4; ++i)
#pragma unroll
        for (int j = 0; j < 4; ++j)
          Sc[(qg + 16 * i) * LDSC + kg + 16 * j] = acc[i][j] * SCALE;
    }
    __syncthreads();
    // ---- add attention mask (coalesced: lanes sweep k) ----
    {
      const int kk = t & 63;
      const int qb_ = t >> 6;      // 0..3
#pragma unroll
      for (int st = 0; st < QT / 4; ++st) {
        const int q = qb_ + st * 4;
        Sc[q * LDSC + kk] += mg[(long)q * S + k0 + kk];
      }
    }
    __syncthreads();
    // ---- online softmax: one thread per row ----
    if (t < QT) {
      const float m_old = mrow[t];
      float mx = m_old;
      for (int k = 0; k < KT; ++k) mx = fmaxf(mx, Sc[t * LDSC + k]);
      const float al = __expf(m_old - mx);  // 0 on first tile (m_old = -inf)
      float sum = 0.f;
      for (int k = 0; k < KT; ++k) {
        const float p = __expf(Sc[t * LDSC + k] - mx);
        Sc[t * LDSC + k] = p;
        sum += p;
      }
      mrow[t] = mx;
      lrow[t] = lrow[t] * al + sum;
      arow[t] = al;
    }
    __syncthreads();
    // ---- rescale O, accumulate PV ----
    {
#pragma unroll
      for (int i = 0; i < 2; ++i) {
        const float al = arow[qg2 + 32 * i];
#pragma unroll
        for (int j = 0; j < 4; ++j) O[i][j] *= al;
      }
      for (int k = 0; k < KT; ++k) {
        const float4 vv = *(const float4*)&Vs[k * LDK + dg * 4];
        const float p0 = Sc[qg2 * LDSC + k];
        const float p1 = Sc[(qg2 + 32) * LDSC + k];
        O[0][0] += p0 * vv.x; O[0][1] += p0 * vv.y; O[0][2] += p0 * vv.z; O[0][3] += p0 * vv.w;
        O[1][0] += p1 * vv.x; O[1][1] += p1 * vv.y; O[1][2] += p1 * vv.z; O[1][3] += p1 * vv.w;
      }
    }
  }
  __syncthreads();
#pragma unroll
  for (int i = 0; i < 2; ++i) {
    const int q = qg2 + 32 * i;
    const float inv = 1.f / lrow[q];
    float4 o;
    o.x = O[i][0] * inv; o.y = O[i][1] * inv; o.z = O[i][2] * inv; o.w = O[i][3] * inv;
    *(float4*)&attn_out[((long)b * S + q0 + q) * H + h * HS + dg * 4] = o;  // [B][S][H]
  }
}

// ---------------- Kernel 3: attn @ Wf + bf + residual + LayerNorm ----------
__global__ __launch_bounds__(128) void out_kernel(
    const float* __restrict__ attn, const float* __restrict__ item,
    const float* __restrict__ Wf, const float* __restrict__ bfv,
    const float* __restrict__ lnw, const float* __restrict__ lnb,
    float* __restrict__ out)
{
  __shared__ float ar[H];
  __shared__ float red[2];
  __shared__ float red2[2];
  const int c = threadIdx.x;
  const long r = blockIdx.x;
  ar[c] = attn[r * H + c];
  __syncthreads();
  float acc = bfv[c];
  for (int k = 0; k < H; k += 4) {
    acc += ar[k] * Wf[k * H + c]
         + ar[k + 1] * Wf[(k + 1) * H + c]
         + ar[k + 2] * Wf[(k + 2) * H + c]
         + ar[k + 3] * Wf[(k + 3) * H + c];
  }
  const float y = acc + item[r * H + c];
  float s = y;
#pragma unroll
  for (int off = 32; off > 0; off >>= 1) s += __shfl_down(s, off, 64);
  if ((c & 63) == 0) red[c >> 6] = s;
  __syncthreads();
  const float u = (red[0] + red[1]) * (1.f / H);
  const float dy = y - u;
  float s2 = dy * dy;
#pragma unroll
  for (int off = 32; off > 0; off >>= 1) s2 += __shfl_down(s2, off, 64);
  if ((c & 63) == 0) red2[c >> 6] = s2;
  __syncthreads();
  const float var = (red2[0] + red2[1]) * (1.f / H);
  out[r * H + c] = lnw[c] * (dy / sqrtf(var + EPS)) + lnb[c];
}

extern "C" void kernel_launch(void* const* d_in, const int* in_sizes, int n_in,
                              void* d_out, int out_size, void* d_ws, size_t ws_size,
                              hipStream_t stream) {
  const float* item = (const float*)d_in[0];
  const float* beh  = (const float*)d_in[1];
  const float* mask = (const float*)d_in[2];
  const float* Wq  = (const float*)d_in[3];  const float* bq  = (const float*)d_in[4];
  const float* Wk  = (const float*)d_in[5];  const float* bk  = (const float*)d_in[6];
  const float* Wv  = (const float*)d_in[7];  const float* bv  = (const float*)d_in[8];
  const float* Wqb = (const float*)d_in[9];  const float* bqb = (const float*)d_in[10];
  const float* Wkb = (const float*)d_in[11]; const float* bkb = (const float*)d_in[12];
  // d_in[13]/d_in[14] = Wvb/bvb: computed in reference forward but unused downstream
  const float* Wf  = (const float*)d_in[15]; const float* bfv = (const float*)d_in[16];
  const float* lnw = (const float*)d_in[17]; const float* lnb = (const float*)d_in[18];
  float* out = (float*)d_out;

  float* ws = (float*)d_ws;
  const size_t NE = (size_t)B * S * H;  // 2,097,152
  float* Qw  = ws;           float* Kw  = ws + NE;     float* Vw = ws + 2 * NE;
  float* Qbw = ws + 3 * NE;  float* Kbw = ws + 4 * NE; float* attn = ws + 5 * NE;

  proj_kernel<<<dim3((B * S) / 16), 256, 0, stream>>>(
      item, beh, Wq, bq, Wk, bk, Wv, bv, Wqb, bqb, Wkb, bkb, Qw, Kw, Vw, Qbw, Kbw);
  attn_kernel<<<dim3(B * NH, S / QT), 256, 0, stream>>>(
      Qw, Kw, Vw, Qbw, Kbw, mask, attn);
  out_kernel<<<dim3(B * S), 128, 0, stream>>>(
      attn, item, Wf, bfv, lnw, lnb, out);
}

// Round 2
// 380.856 us; speedup vs baseline: 2.2167x; 2.2167x over previous
//
#include <hip/hip_runtime.h>
#include <math.h>

typedef unsigned short ushort_t;
typedef __attribute__((ext_vector_type(8))) short bf16x8;
typedef __attribute__((ext_vector_type(4))) float f32x4;

namespace {
constexpr int B = 8, S = 2048, H = 128, NH = 4, HS = 32;
constexpr float EPS = 1e-8f;
constexpr float SCALE = 0.17677669529663687f;  // 1/sqrt(32)
constexpr int QT = 32, KT = 64;
constexpr int NE = B * S * H;  // 2,097,152 elements per tensor
}

__device__ __forceinline__ ushort_t f2bf(float f) {
  unsigned u = __float_as_uint(f);
  unsigned r = (u + 0x7FFFu + ((u >> 16) & 1u)) >> 16;  // RNE
  return (ushort_t)r;
}

__device__ __forceinline__ f32x4 mfma16(bf16x8 a, bf16x8 b, f32x4 c) {
  return __builtin_amdgcn_mfma_f32_16x16x32_bf16(a, b, c, 0, 0, 0);
}

// ---------- Kernel 0: transpose+convert all 6 weight matrices to bf16 Wt[n][k] ----------
__global__ __launch_bounds__(256) void wcvt_kernel(
    const float* __restrict__ Wq, const float* __restrict__ Wk, const float* __restrict__ Wv,
    const float* __restrict__ Wqb, const float* __restrict__ Wkb, const float* __restrict__ Wf,
    ushort_t* __restrict__ Wt)
{
  const float* Ws[6] = {Wq, Wk, Wv, Wqb, Wkb, Wf};
  const int m = blockIdx.y;
  const int kb = blockIdx.x;           // 32-row slab of k
  const float* W = Ws[m];
  __shared__ float T[32 * 132];
  const int t = threadIdx.x;
#pragma unroll
  for (int u = 0; u < 4; ++u) {        // 32 rows x 32 float4
    const int idx = u * 256 + t;
    const int row = idx >> 5, c4 = idx & 31;
    const float4 v = *(const float4*)&W[(kb * 32 + row) * H + c4 * 4];
    *(float4*)&T[row * 132 + c4 * 4] = v;
  }
  __syncthreads();
#pragma unroll
  for (int u = 0; u < 16; ++u) {       // 128 n x 32 kk
    const int idx = u * 256 + t;
    const int n = idx >> 5, kk = idx & 31;
    Wt[m * (H * H) + n * H + kb * 32 + kk] = f2bf(T[kk * 132 + n]);
  }
}

// ---------- Kernel 1: 5 projections via MFMA, bf16 outputs in attention-friendly layouts ----
// Q,K,Qb,Kb: [B][NH][S][HS] bf16 ; V: transposed [B][NH][HS][S] bf16
__global__ __launch_bounds__(256) void proj_kernel(
    const float* __restrict__ item, const float* __restrict__ beh,
    const ushort_t* __restrict__ Wt,
    const float* __restrict__ bq, const float* __restrict__ bk, const float* __restrict__ bv,
    const float* __restrict__ bqb, const float* __restrict__ bkb,
    ushort_t* __restrict__ Qo, ushort_t* __restrict__ Ko, ushort_t* __restrict__ Qbo,
    ushort_t* __restrict__ Kbo, ushort_t* __restrict__ Vto)
{
  __shared__ ushort_t Xi[64 * 136];
  __shared__ ushort_t Xb[64 * 136];
  const int t = threadIdx.x;
  const long r0 = (long)blockIdx.x * 64;
#pragma unroll
  for (int u = 0; u < 8; ++u) {        // 64 rows x 32 float4 per matrix
    const int idx = u * 256 + t;
    const int row = idx >> 5, c4 = idx & 31;
    const float4 vi = *(const float4*)&item[(r0 + row) * H + c4 * 4];
    const float4 vb = *(const float4*)&beh[(r0 + row) * H + c4 * 4];
    unsigned long long pi = (unsigned long long)f2bf(vi.x) | ((unsigned long long)f2bf(vi.y) << 16)
        | ((unsigned long long)f2bf(vi.z) << 32) | ((unsigned long long)f2bf(vi.w) << 48);
    unsigned long long pb = (unsigned long long)f2bf(vb.x) | ((unsigned long long)f2bf(vb.y) << 16)
        | ((unsigned long long)f2bf(vb.z) << 32) | ((unsigned long long)f2bf(vb.w) << 48);
    *(unsigned long long*)&Xi[row * 136 + c4 * 4] = pi;
    *(unsigned long long*)&Xb[row * 136 + c4 * 4] = pb;
  }
  __syncthreads();

  const int w = t >> 6, l = t & 63, l15 = l & 15, quad = l >> 4;
  const int bb = (int)(r0 >> 11);
  const int s0 = (int)(r0 & (S - 1));
  const float* bias[5] = {bq, bk, bv, bqb, bkb};
  ushort_t* dsts[5] = {Qo, Ko, Vto, Qbo, Kbo};

  bf16x8 af[4][4];
#pragma unroll
  for (int mt = 0; mt < 4; ++mt)
#pragma unroll
    for (int ks = 0; ks < 4; ++ks)
      af[mt][ks] = *(const bf16x8*)&Xi[(mt * 16 + l15) * 136 + ks * 32 + quad * 8];

  for (int p = 0; p < 5; ++p) {
    if (p == 3) {  // switch A-operand to behavior embeds
#pragma unroll
      for (int mt = 0; mt < 4; ++mt)
#pragma unroll
        for (int ks = 0; ks < 4; ++ks)
          af[mt][ks] = *(const bf16x8*)&Xb[(mt * 16 + l15) * 136 + ks * 32 + quad * 8];
    }
    f32x4 acc[4][2];
    float bcol[2];
#pragma unroll
    for (int nt = 0; nt < 2; ++nt) {
      bcol[nt] = bias[p][w * 32 + nt * 16 + l15];
#pragma unroll
      for (int mt = 0; mt < 4; ++mt)
        acc[mt][nt] = (f32x4){bcol[nt], bcol[nt], bcol[nt], bcol[nt]};
    }
    const ushort_t* Wp = Wt + p * (H * H);
#pragma unroll
    for (int ks = 0; ks < 4; ++ks) {
      bf16x8 bfr[2];
#pragma unroll
      for (int nt = 0; nt < 2; ++nt)
        bfr[nt] = *(const bf16x8*)&Wp[(w * 32 + nt * 16 + l15) * H + ks * 32 + quad * 8];
#pragma unroll
      for (int mt = 0; mt < 4; ++mt)
#pragma unroll
        for (int nt = 0; nt < 2; ++nt)
          acc[mt][nt] = mfma16(af[mt][ks], bfr[nt], acc[mt][nt]);
    }
    // epilogue: C layout row = quad*4+reg, col = w*32 + nt*16 + l15 ; head = w, d = nt*16+l15
    ushort_t* dst = dsts[p];
#pragma unroll
    for (int mt = 0; mt < 4; ++mt)
#pragma unroll
      for (int nt = 0; nt < 2; ++nt)
#pragma unroll
        for (int r = 0; r < 4; ++r) {
          const int s = s0 + mt * 16 + quad * 4 + r;
          const int d = nt * 16 + l15;
          long idx;
          if (p == 2)  // V transposed: [b][h][d][s]
            idx = ((long)(bb * NH + w) * HS + d) * S + s;
          else         // [b][h][s][d]
            idx = ((long)(bb * NH + w) * S + s) * HS + d;
          dst[idx] = f2bf(acc[mt][nt][r]);
        }
  }
}

// ---------- Kernel 2: MFMA flash attention, wave = head, no __syncthreads ----------
__global__ __launch_bounds__(256) void attn_kernel(
    const ushort_t* __restrict__ Q, const ushort_t* __restrict__ K,
    const ushort_t* __restrict__ Qb, const ushort_t* __restrict__ Kb,
    const ushort_t* __restrict__ Vt, const float* __restrict__ mask,
    ushort_t* __restrict__ attn_out)
{
  __shared__ ushort_t Pb[NH][32 * 72];   // per-wave P scratch (A-layout rows q, cols k)
  const int t = threadIdx.x;
  const int w = t >> 6;                  // head
  const int l = t & 63, l15 = l & 15, quad = l >> 4;
  const int q0 = blockIdx.x * QT;
  const int b = blockIdx.y;
  const long hQ = (long)(b * NH + w) * S * HS;
  const long hV = (long)(b * NH + w) * HS * S;

  // persistent Q/Qb A-fragments
  bf16x8 qf[2], qbf[2];
#pragma unroll
  for (int mt = 0; mt < 2; ++mt) {
    qf[mt]  = *(const bf16x8*)&Q[hQ + (long)(q0 + mt * 16 + l15) * HS + quad * 8];
    qbf[mt] = *(const bf16x8*)&Qb[hQ + (long)(q0 + mt * 16 + l15) * HS + quad * 8];
  }
  const float* mbase[2][4];
#pragma unroll
  for (int mt = 0; mt < 2; ++mt)
#pragma unroll
    for (int r = 0; r < 4; ++r)
      mbase[mt][r] = mask + ((long)b * S + q0 + mt * 16 + quad * 4 + r) * S + l15;

  float mold[2][4], lsum[2][4];
  f32x4 O[2][2];
#pragma unroll
  for (int mt = 0; mt < 2; ++mt) {
#pragma unroll
    for (int r = 0; r < 4; ++r) { mold[mt][r] = -1e30f; lsum[mt][r] = 0.f; }
#pragma unroll
    for (int dt = 0; dt < 2; ++dt) O[mt][dt] = (f32x4){0.f, 0.f, 0.f, 0.f};
  }
  ushort_t* Pw = Pb[w];

  for (int kt = 0; kt < S / KT; ++kt) {
    const int k0 = kt * KT;
    // mask -> C-layout registers (issued early)
    float mk[2][4][4];  // [mt][nt][r]
#pragma unroll
    for (int mt = 0; mt < 2; ++mt)
#pragma unroll
      for (int r = 0; r < 4; ++r)
#pragma unroll
        for (int nt = 0; nt < 4; ++nt)
          mk[mt][nt][r] = mbase[mt][r][k0 + nt * 16];
    // K/Kb B-frags and V B-frags
    bf16x8 kf[4], kbf[4], vf[2][2];
#pragma unroll
    for (int nt = 0; nt < 4; ++nt) {
      kf[nt]  = *(const bf16x8*)&K[hQ + (long)(k0 + nt * 16 + l15) * HS + quad * 8];
      kbf[nt] = *(const bf16x8*)&Kb[hQ + (long)(k0 + nt * 16 + l15) * HS + quad * 8];
    }
#pragma unroll
    for (int dt = 0; dt < 2; ++dt)
#pragma unroll
      for (int ks = 0; ks < 2; ++ks)
        vf[dt][ks] = *(const bf16x8*)&Vt[hV + (long)(dt * 16 + l15) * S + k0 + ks * 32 + quad * 8];

    // scores
    f32x4 sc[2][4];
#pragma unroll
    for (int mt = 0; mt < 2; ++mt)
#pragma unroll
      for (int nt = 0; nt < 4; ++nt) {
        f32x4 z = (f32x4){0.f, 0.f, 0.f, 0.f};
        z = mfma16(qf[mt], kf[nt], z);
        z = mfma16(qbf[mt], kbf[nt], z);
        sc[mt][nt] = z;
      }
    // scale + mask
#pragma unroll
    for (int mt = 0; mt < 2; ++mt)
#pragma unroll
      for (int nt = 0; nt < 4; ++nt)
#pragma unroll
        for (int r = 0; r < 4; ++r)
          sc[mt][nt][r] = sc[mt][nt][r] * SCALE + mk[mt][nt][r];
    // online softmax in registers
    float alpha[2][4];
#pragma unroll
    for (int mt = 0; mt < 2; ++mt)
#pragma unroll
      for (int r = 0; r < 4; ++r) {
        float rm = fmaxf(fmaxf(sc[mt][0][r], sc[mt][1][r]), fmaxf(sc[mt][2][r], sc[mt][3][r]));
        rm = fmaxf(rm, __shfl_xor(rm, 1));
        rm = fmaxf(rm, __shfl_xor(rm, 2));
        rm = fmaxf(rm, __shfl_xor(rm, 4));
        rm = fmaxf(rm, __shfl_xor(rm, 8));
        const float mnew = fmaxf(mold[mt][r], rm);
        alpha[mt][r] = __expf(mold[mt][r] - mnew);
        float rs = 0.f;
#pragma unroll
        for (int nt = 0; nt < 4; ++nt) {
          const float p = __expf(sc[mt][nt][r] - mnew);
          sc[mt][nt][r] = p;
          rs += p;
        }
        rs += __shfl_xor(rs, 1);
        rs += __shfl_xor(rs, 2);
        rs += __shfl_xor(rs, 4);
        rs += __shfl_xor(rs, 8);
        lsum[mt][r] = lsum[mt][r] * alpha[mt][r] + rs;
        mold[mt][r] = mnew;
      }
    // rescale O, write P (bf16) to per-wave LDS
#pragma unroll
    for (int mt = 0; mt < 2; ++mt)
#pragma unroll
      for (int dt = 0; dt < 2; ++dt)
#pragma unroll
        for (int r = 0; r < 4; ++r)
          O[mt][dt][r] *= alpha[mt][r];
#pragma unroll
    for (int mt = 0; mt < 2; ++mt)
#pragma unroll
      for (int nt = 0; nt < 4; ++nt)
#pragma unroll
        for (int r = 0; r < 4; ++r)
          Pw[(mt * 16 + quad * 4 + r) * 72 + nt * 16 + l15] = f2bf(sc[mt][nt][r]);
    // P A-frags (intra-wave LDS dependency only) + PV
#pragma unroll
    for (int mt = 0; mt < 2; ++mt) {
      bf16x8 pf[2];
#pragma unroll
      for (int ks = 0; ks < 2; ++ks)
        pf[ks] = *(const bf16x8*)&Pw[(mt * 16 + l15) * 72 + ks * 32 + quad * 8];
#pragma unroll
      for (int dt = 0; dt < 2; ++dt)
#pragma unroll
        for (int ks = 0; ks < 2; ++ks)
          O[mt][dt] = mfma16(pf[ks], vf[dt][ks], O[mt][dt]);
    }
  }
  // epilogue: O / l -> bf16 attn workspace [B][S][H]
#pragma unroll
  for (int mt = 0; mt < 2; ++mt)
#pragma unroll
    for (int r = 0; r < 4; ++r) {
      const float inv = 1.f / lsum[mt][r];
      const long row = (long)b * S + q0 + mt * 16 + quad * 4 + r;
#pragma unroll
      for (int dt = 0; dt < 2; ++dt)
        attn_out[row * H + w * 32 + dt * 16 + l15] = f2bf(O[mt][dt][r] * inv);
    }
}

// ---------- Kernel 3: attn @ Wf + bias + residual + LayerNorm (MFMA) ----------
__global__ __launch_bounds__(256) void out_kernel(
    const ushort_t* __restrict__ attn, const float* __restrict__ item,
    const ushort_t* __restrict__ Wft, const float* __restrict__ bf_,
    const float* __restrict__ lnw, const float* __restrict__ lnb,
    float* __restrict__ out)
{
  __shared__ ushort_t As[64 * 136];
  __shared__ float Ys[64 * 132];
  const int t = threadIdx.x;
  const long r0 = (long)blockIdx.x * 64;
#pragma unroll
  for (int u = 0; u < 4; ++u) {        // 64 rows x 16 chunks of 8 bf16
    const int idx = u * 256 + t;
    const int row = idx >> 4, c8 = idx & 15;
    *(uint4*)&As[row * 136 + c8 * 8] = *(const uint4*)&attn[(r0 + row) * H + c8 * 8];
  }
  __syncthreads();
  const int w = t >> 6, l = t & 63, l15 = l & 15, quad = l >> 4;
  f32x4 acc[4][2];
#pragma unroll
  for (int nt = 0; nt < 2; ++nt) {
    const float bcol = bf_[w * 32 + nt * 16 + l15];
#pragma unroll
    for (int mt = 0; mt < 4; ++mt)
      acc[mt][nt] = (f32x4){bcol, bcol, bcol, bcol};
  }
#pragma unroll
  for (int ks = 0; ks < 4; ++ks) {
    bf16x8 bfr[2];
#pragma unroll
    for (int nt = 0; nt < 2; ++nt)
      bfr[nt] = *(const bf16x8*)&Wft[(w * 32 + nt * 16 + l15) * H + ks * 32 + quad * 8];
#pragma unroll
    for (int mt = 0; mt < 4; ++mt) {
      const bf16x8 a = *(const bf16x8*)&As[(mt * 16 + l15) * 136 + ks * 32 + quad * 8];
      for (int nt = 0; nt < 2; ++nt)
        acc[mt][nt] = mfma16(a, bfr[nt], acc[mt][nt]);
    }
  }
  // Y = acc + item -> LDS
#pragma unroll
  for (int mt = 0; mt < 4; ++mt)
#pragma unroll
    for (int nt = 0; nt < 2; ++nt)
#pragma unroll
      for (int r = 0; r < 4; ++r) {
        const int rl = mt * 16 + quad * 4 + r;
        const int col = w * 32 + nt * 16 + l15;
        Ys[rl * 132 + col] = acc[mt][nt][r] + item[(r0 + rl) * H + col];
      }
  __syncthreads();
  // LayerNorm: 4 threads per row, two-pass
  const int rl = t >> 2, ch = t & 3;
  float v[32];
#pragma unroll
  for (int g = 0; g < 8; ++g) {
    const float4 y = *(const float4*)&Ys[rl * 132 + ch * 32 + g * 4];
    v[g * 4 + 0] = y.x; v[g * 4 + 1] = y.y; v[g * 4 + 2] = y.z; v[g * 4 + 3] = y.w;
  }
  float s = 0.f;
#pragma unroll
  for (int i = 0; i < 32; ++i) s += v[i];
  s += __shfl_xor(s, 1);
  s += __shfl_xor(s, 2);
  const float u_ = s * (1.f / H);
  float s2 = 0.f;
#pragma unroll
  for (int i = 0; i < 32; ++i) { const float d = v[i] - u_; s2 += d * d; }
  s2 += __shfl_xor(s2, 1);
  s2 += __shfl_xor(s2, 2);
  const float rinv = rsqrtf(s2 * (1.f / H) + EPS);
#pragma unroll
  for (int g = 0; g < 8; ++g) {
    float4 o;
    const int col = ch * 32 + g * 4;
    o.x = lnw[col + 0] * ((v[g * 4 + 0] - u_) * rinv) + lnb[col + 0];
    o.y = lnw[col + 1] * ((v[g * 4 + 1] - u_) * rinv) + lnb[col + 1];
    o.z = lnw[col + 2] * ((v[g * 4 + 2] - u_) * rinv) + lnb[col + 2];
    o.w = lnw[col + 3] * ((v[g * 4 + 3] - u_) * rinv) + lnb[col + 3];
    *(float4*)&out[(r0 + rl) * H + col] = o;
  }
}

extern "C" void kernel_launch(void* const* d_in, const int* in_sizes, int n_in,
                              void* d_out, int out_size, void* d_ws, size_t ws_size,
                              hipStream_t stream) {
  const float* item = (const float*)d_in[0];
  const float* beh  = (const float*)d_in[1];
  const float* mask = (const float*)d_in[2];
  const float* Wq  = (const float*)d_in[3];  const float* bq  = (const float*)d_in[4];
  const float* Wk  = (const float*)d_in[5];  const float* bk  = (const float*)d_in[6];
  const float* Wv  = (const float*)d_in[7];  const float* bv  = (const float*)d_in[8];
  const float* Wqb = (const float*)d_in[9];  const float* bqb = (const float*)d_in[10];
  const float* Wkb = (const float*)d_in[11]; const float* bkb = (const float*)d_in[12];
  // d_in[13]/[14] = Wvb/bvb: dead code in the reference
  const float* Wf  = (const float*)d_in[15]; const float* bfv = (const float*)d_in[16];
  const float* lnw = (const float*)d_in[17]; const float* lnb = (const float*)d_in[18];
  float* out = (float*)d_out;

  ushort_t* ws = (ushort_t*)d_ws;
  ushort_t* Qw   = ws;
  ushort_t* Kw   = Qw + NE;
  ushort_t* Qbw  = Kw + NE;
  ushort_t* Kbw  = Qbw + NE;
  ushort_t* Vtw  = Kbw + NE;
  ushort_t* Attw = Vtw + NE;
  ushort_t* Wt   = Attw + NE;   // 6 * H*H bf16

  wcvt_kernel<<<dim3(4, 6), 256, 0, stream>>>(Wq, Wk, Wv, Wqb, Wkb, Wf, Wt);
  proj_kernel<<<dim3((B * S) / 64), 256, 0, stream>>>(
      item, beh, Wt, bq, bk, bv, bqb, bkb, Qw, Kw, Qbw, Kbw, Vtw);
  attn_kernel<<<dim3(S / QT, B), 256, 0, stream>>>(
      Qw, Kw, Qbw, Kbw, Vtw, mask, Attw);
  out_kernel<<<dim3((B * S) / 64), 256, 0, stream>>>(
      Attw, item, Wt + 5 * H * H, bfv, lnw, lnb, out);
}

// Round 4
// 379.438 us; speedup vs baseline: 2.2250x; 1.0037x over previous
//
#include <hip/hip_runtime.h>
#include <math.h>

typedef unsigned short ushort_t;
typedef __attribute__((ext_vector_type(8))) short bf16x8;
typedef __attribute__((ext_vector_type(4))) float f32x4;

namespace {
constexpr int B = 8, S = 2048, H = 128, NH = 4, HS = 32;
constexpr float EPS = 1e-8f;
constexpr float SCALE = 0.17677669529663687f;  // 1/sqrt(32)
constexpr int QT = 16, KT = 64;
constexpr int NE = B * S * H;  // 2,097,152 elements per tensor
}

__device__ __forceinline__ ushort_t f2bf(float f) {
  unsigned u = __float_as_uint(f);
  unsigned r = (u + 0x7FFFu + ((u >> 16) & 1u)) >> 16;  // RNE
  return (ushort_t)r;
}

__device__ __forceinline__ f32x4 mfma16(bf16x8 a, bf16x8 b, f32x4 c) {
  return __builtin_amdgcn_mfma_f32_16x16x32_bf16(a, b, c, 0, 0, 0);
}

// ---------- Kernel 0: transpose+convert weights to bf16 Wt[n][k]; SCALE folded into Wq/Wqb ----
__global__ __launch_bounds__(256) void wcvt_kernel(
    const float* __restrict__ Wq, const float* __restrict__ Wk, const float* __restrict__ Wv,
    const float* __restrict__ Wqb, const float* __restrict__ Wkb, const float* __restrict__ Wf,
    ushort_t* __restrict__ Wt)
{
  const float* Ws[6] = {Wq, Wk, Wv, Wqb, Wkb, Wf};
  const float scl[6] = {SCALE, 1.f, 1.f, SCALE, 1.f, 1.f};
  const int m = blockIdx.y;
  const int kb = blockIdx.x;           // 32-row slab of k
  const float* W = Ws[m];
  const float sc = scl[m];
  __shared__ float T[32 * 132];
  const int t = threadIdx.x;
#pragma unroll
  for (int u = 0; u < 4; ++u) {        // 32 rows x 32 float4
    const int idx = u * 256 + t;
    const int row = idx >> 5, c4 = idx & 31;
    const float4 v = *(const float4*)&W[(kb * 32 + row) * H + c4 * 4];
    *(float4*)&T[row * 132 + c4 * 4] = v;
  }
  __syncthreads();
#pragma unroll
  for (int u = 0; u < 16; ++u) {       // 128 n x 32 kk
    const int idx = u * 256 + t;
    const int n = idx >> 5, kk = idx & 31;
    Wt[m * (H * H) + n * H + kb * 32 + kk] = f2bf(T[kk * 132 + n] * sc);
  }
}

// ---------- Kernel 1: 5 projections via MFMA; coalesced stores via LDS repack ----------
// Q,K,Qb,Kb: [B][NH][S][HS] bf16 (Q/Qb pre-scaled) ; V: transposed [B][NH][HS][S] bf16
__global__ __launch_bounds__(256) void proj_kernel(
    const float* __restrict__ item, const float* __restrict__ beh,
    const ushort_t* __restrict__ Wt,
    const float* __restrict__ bq, const float* __restrict__ bk, const float* __restrict__ bv,
    const float* __restrict__ bqb, const float* __restrict__ bkb,
    ushort_t* __restrict__ Qo, ushort_t* __restrict__ Ko, ushort_t* __restrict__ Qbo,
    ushort_t* __restrict__ Kbo, ushort_t* __restrict__ Vto)
{
  __shared__ ushort_t Xi[32 * 136];
  __shared__ ushort_t Xb[32 * 136];
  __shared__ ushort_t Yb[32 * 136];
  const int t = threadIdx.x;
  const long r0 = (long)blockIdx.x * 32;
#pragma unroll
  for (int u = 0; u < 4; ++u) {        // 32 rows x 32 float4 per matrix (1024 float4 each)
    const int idx = u * 256 + t;
    const int row = idx >> 5, c4 = idx & 31;
    const float4 vi = *(const float4*)&item[(r0 + row) * H + c4 * 4];
    const float4 vb = *(const float4*)&beh[(r0 + row) * H + c4 * 4];
    unsigned long long pi = (unsigned long long)f2bf(vi.x) | ((unsigned long long)f2bf(vi.y) << 16)
        | ((unsigned long long)f2bf(vi.z) << 32) | ((unsigned long long)f2bf(vi.w) << 48);
    unsigned long long pb = (unsigned long long)f2bf(vb.x) | ((unsigned long long)f2bf(vb.y) << 16)
        | ((unsigned long long)f2bf(vb.z) << 32) | ((unsigned long long)f2bf(vb.w) << 48);
    *(unsigned long long*)&Xi[row * 136 + c4 * 4] = pi;
    *(unsigned long long*)&Xb[row * 136 + c4 * 4] = pb;
  }
  __syncthreads();

  const int w = t >> 6, l = t & 63, l15 = l & 15, quad = l >> 4;
  const int bb = (int)(r0 >> 11);
  const int s0 = (int)(r0 & (S - 1));
  const float* bias[5] = {bq, bk, bv, bqb, bkb};
  const float bscale[5] = {SCALE, 1.f, 1.f, SCALE, 1.f};
  ushort_t* dsts[5] = {Qo, Ko, Vto, Qbo, Kbo};

  bf16x8 afi[2][4], afb[2][4];
#pragma unroll
  for (int mt = 0; mt < 2; ++mt)
#pragma unroll
    for (int ks = 0; ks < 4; ++ks) {
      afi[mt][ks] = *(const bf16x8*)&Xi[(mt * 16 + l15) * 136 + ks * 32 + quad * 8];
      afb[mt][ks] = *(const bf16x8*)&Xb[(mt * 16 + l15) * 136 + ks * 32 + quad * 8];
    }

  for (int p = 0; p < 5; ++p) {
    f32x4 acc[2][2];
#pragma unroll
    for (int nt = 0; nt < 2; ++nt) {
      const float bcol = bias[p][w * 32 + nt * 16 + l15] * bscale[p];
#pragma unroll
      for (int mt = 0; mt < 2; ++mt)
        acc[mt][nt] = (f32x4){bcol, bcol, bcol, bcol};
    }
    const ushort_t* Wp = Wt + p * (H * H);
    const bf16x8 (*af)[4] = (p < 3) ? afi : afb;
#pragma unroll
    for (int ks = 0; ks < 4; ++ks) {
      bf16x8 bfr[2];
#pragma unroll
      for (int nt = 0; nt < 2; ++nt)
        bfr[nt] = *(const bf16x8*)&Wp[(w * 32 + nt * 16 + l15) * H + ks * 32 + quad * 8];
#pragma unroll
      for (int mt = 0; mt < 2; ++mt)
#pragma unroll
        for (int nt = 0; nt < 2; ++nt)
          acc[mt][nt] = mfma16(af[mt][ks], bfr[nt], acc[mt][nt]);
    }
    // repack through LDS: Yb[row][col]
#pragma unroll
    for (int mt = 0; mt < 2; ++mt)
#pragma unroll
      for (int nt = 0; nt < 2; ++nt)
#pragma unroll
        for (int r = 0; r < 4; ++r)
          Yb[(mt * 16 + quad * 4 + r) * 136 + w * 32 + nt * 16 + l15] = f2bf(acc[mt][nt][r]);
    __syncthreads();
    ushort_t* dst = dsts[p];
    if (p == 2) {
      // Vt [b][h][d][s]: thread t -> d = t>>1, 16 consecutive s
      const int d = t >> 1, sh = (t & 1) * 16;
      ushort_t tmp[16];
#pragma unroll
      for (int i = 0; i < 16; ++i) tmp[i] = Yb[(sh + i) * 136 + d];
      const long gidx = ((long)(bb * NH + (d >> 5)) * HS + (d & 31)) * S + s0 + sh;
      *(uint4*)&dst[gidx] = *(const uint4*)&tmp[0];
      *(uint4*)&dst[gidx + 8] = *(const uint4*)&tmp[8];
    } else {
      // [b][h][s][d]: thread t -> row = t>>3, 16 consecutive cols
      const int row = t >> 3, cb = (t & 7) * 16;
      const int h = cb >> 5, dd = cb & 31;
      const long gidx = ((long)(bb * NH + h) * S + s0 + row) * HS + dd;
      *(uint4*)&dst[gidx] = *(const uint4*)&Yb[row * 136 + cb];
      *(uint4*)&dst[gidx + 8] = *(const uint4*)&Yb[row * 136 + cb + 8];
    }
    __syncthreads();
  }
}

// ---------- Kernel 2: MFMA flash attention, wave = head, QT=16, no __syncthreads ----------
__global__ __launch_bounds__(256, 4) void attn_kernel(
    const ushort_t* __restrict__ Q, const ushort_t* __restrict__ K,
    const ushort_t* __restrict__ Qb, const ushort_t* __restrict__ Kb,
    const ushort_t* __restrict__ Vt, const float* __restrict__ mask,
    ushort_t* __restrict__ attn_out)
{
  __shared__ ushort_t Pb[NH][16 * 72];   // per-wave P scratch
  const int t = threadIdx.x;
  const int w = t >> 6;                  // head
  const int l = t & 63, l15 = l & 15, quad = l >> 4;
  const int q0 = blockIdx.x * QT;
  const int b = blockIdx.y;
  const long hQ = (long)(b * NH + w) * S * HS;
  const long hV = (long)(b * NH + w) * HS * S;

  // persistent Q/Qb A-fragments (Q pre-scaled by 1/sqrt(HS))
  const bf16x8 qf  = *(const bf16x8*)&Q[hQ + (long)(q0 + l15) * HS + quad * 8];
  const bf16x8 qbf = *(const bf16x8*)&Qb[hQ + (long)(q0 + l15) * HS + quad * 8];

  const float* mrow[4];
#pragma unroll
  for (int r = 0; r < 4; ++r)
    mrow[r] = mask + ((long)b * S + q0 + quad * 4 + r) * S + l15;

  float mold[4], lsum[4];
  f32x4 O[2];
#pragma unroll
  for (int r = 0; r < 4; ++r) { mold[r] = -1e30f; lsum[r] = 0.f; }
#pragma unroll
  for (int dt = 0; dt < 2; ++dt) O[dt] = (f32x4){0.f, 0.f, 0.f, 0.f};
  ushort_t* Pw = Pb[w];

  for (int kt = 0; kt < S / KT; ++kt) {
    const int k0 = kt * KT;
    // score accumulators init directly with mask (C-operand of MFMA)
    f32x4 sc[4];
#pragma unroll
    for (int nt = 0; nt < 4; ++nt)
#pragma unroll
      for (int r = 0; r < 4; ++r)
        sc[nt][r] = mrow[r][k0 + nt * 16];
    // K/Kb B-frags and V B-frags
    bf16x8 kf[4], kbf[4], vf[2][2];
#pragma unroll
    for (int nt = 0; nt < 4; ++nt) {
      kf[nt]  = *(const bf16x8*)&K[hQ + (long)(k0 + nt * 16 + l15) * HS + quad * 8];
      kbf[nt] = *(const bf16x8*)&Kb[hQ + (long)(k0 + nt * 16 + l15) * HS + quad * 8];
    }
#pragma unroll
    for (int dt = 0; dt < 2; ++dt)
#pragma unroll
      for (int ks = 0; ks < 2; ++ks)
        vf[dt][ks] = *(const bf16x8*)&Vt[hV + (long)(dt * 16 + l15) * S + k0 + ks * 32 + quad * 8];
    // scores = Q'K^T + Qb'Kb^T + mask
#pragma unroll
    for (int nt = 0; nt < 4; ++nt) {
      sc[nt] = mfma16(qbf, kbf[nt], sc[nt]);
      sc[nt] = mfma16(qf, kf[nt], sc[nt]);
    }
    // online softmax in registers
    float alpha[4];
#pragma unroll
    for (int r = 0; r < 4; ++r) {
      float rm = fmaxf(fmaxf(sc[0][r], sc[1][r]), fmaxf(sc[2][r], sc[3][r]));
      rm = fmaxf(rm, __shfl_xor(rm, 1));
      rm = fmaxf(rm, __shfl_xor(rm, 2));
      rm = fmaxf(rm, __shfl_xor(rm, 4));
      rm = fmaxf(rm, __shfl_xor(rm, 8));
      const float mnew = fmaxf(mold[r], rm);
      alpha[r] = __expf(mold[r] - mnew);
      float rs = 0.f;
#pragma unroll
      for (int nt = 0; nt < 4; ++nt) {
        const float p = __expf(sc[nt][r] - mnew);
        sc[nt][r] = p;
        rs += p;
      }
      rs += __shfl_xor(rs, 1);
      rs += __shfl_xor(rs, 2);
      rs += __shfl_xor(rs, 4);
      rs += __shfl_xor(rs, 8);
      lsum[r] = lsum[r] * alpha[r] + rs;
      mold[r] = mnew;
    }
    // rescale O, write P (bf16) to per-wave LDS
#pragma unroll
    for (int dt = 0; dt < 2; ++dt)
#pragma unroll
      for (int r = 0; r < 4; ++r)
        O[dt][r] *= alpha[r];
#pragma unroll
    for (int nt = 0; nt < 4; ++nt)
#pragma unroll
      for (int r = 0; r < 4; ++r)
        Pw[(quad * 4 + r) * 72 + nt * 16 + l15] = f2bf(sc[nt][r]);
    // P A-frags (intra-wave LDS dependency only) + PV
    bf16x8 pf[2];
#pragma unroll
    for (int ks = 0; ks < 2; ++ks)
      pf[ks] = *(const bf16x8*)&Pw[l15 * 72 + ks * 32 + quad * 8];
#pragma unroll
    for (int dt = 0; dt < 2; ++dt)
#pragma unroll
      for (int ks = 0; ks < 2; ++ks)
        O[dt] = mfma16(pf[ks], vf[dt][ks], O[dt]);
  }
  // epilogue: O / l -> bf16 attn workspace [B][S][H]
#pragma unroll
  for (int r = 0; r < 4; ++r) {
    const float inv = 1.f / lsum[r];
    const long row = (long)b * S + q0 + quad * 4 + r;
#pragma unroll
    for (int dt = 0; dt < 2; ++dt)
      attn_out[row * H + w * 32 + dt * 16 + l15] = f2bf(O[dt][r] * inv);
  }
}

// ---------- Kernel 3: attn @ Wf + bias + residual + LayerNorm (MFMA) ----------
__global__ __launch_bounds__(256) void out_kernel(
    const ushort_t* __restrict__ attn, const float* __restrict__ item,
    const ushort_t* __restrict__ Wft, const float* __restrict__ bf_,
    const float* __restrict__ lnw, const float* __restrict__ lnb,
    float* __restrict__ out)
{
  __shared__ ushort_t As[32 * 136];
  __shared__ float Ys[32 * 132];
  const int t = threadIdx.x;
  const long r0 = (long)blockIdx.x * 32;
#pragma unroll
  for (int u = 0; u < 2; ++u) {        // 32 rows x 16 chunks of 8 bf16 (512 total)
    const int idx = u * 256 + t;
    const int row = idx >> 4, c8 = idx & 15;
    *(uint4*)&As[row * 136 + c8 * 8] = *(const uint4*)&attn[(r0 + row) * H + c8 * 8];
  }
  __syncthreads();
  const int w = t >> 6, l = t & 63, l15 = l & 15, quad = l >> 4;
  f32x4 acc[2][2];
#pragma unroll
  for (int nt = 0; nt < 2; ++nt) {
    const float bcol = bf_[w * 32 + nt * 16 + l15];
#pragma unroll
    for (int mt = 0; mt < 2; ++mt)
      acc[mt][nt] = (f32x4){bcol, bcol, bcol, bcol};
  }
#pragma unroll
  for (int ks = 0; ks < 4; ++ks) {
    bf16x8 bfr[2];
#pragma unroll
    for (int nt = 0; nt < 2; ++nt)
      bfr[nt] = *(const bf16x8*)&Wft[(w * 32 + nt * 16 + l15) * H + ks * 32 + quad * 8];
#pragma unroll
    for (int mt = 0; mt < 2; ++mt) {
      const bf16x8 a = *(const bf16x8*)&As[(mt * 16 + l15) * 136 + ks * 32 + quad * 8];
#pragma unroll
      for (int nt = 0; nt < 2; ++nt)
        acc[mt][nt] = mfma16(a, bfr[nt], acc[mt][nt]);
    }
  }
  // Y = acc + item -> LDS
#pragma unroll
  for (int mt = 0; mt < 2; ++mt)
#pragma unroll
    for (int nt = 0; nt < 2; ++nt)
#pragma unroll
      for (int r = 0; r < 4; ++r) {
        const int rl = mt * 16 + quad * 4 + r;
        const int col = w * 32 + nt * 16 + l15;
        Ys[rl * 132 + col] = acc[mt][nt][r] + item[(r0 + rl) * H + col];
      }
  __syncthreads();
  // LayerNorm: 8 threads per row
  const int rl = t >> 3, ch = t & 7;
  float v[16];
#pragma unroll
  for (int g = 0; g < 4; ++g) {
    const float4 y = *(const float4*)&Ys[rl * 132 + ch * 16 + g * 4];
    v[g * 4 + 0] = y.x; v[g * 4 + 1] = y.y; v[g * 4 + 2] = y.z; v[g * 4 + 3] = y.w;
  }
  float s = 0.f;
#pragma unroll
  for (int i = 0; i < 16; ++i) s += v[i];
  s += __shfl_xor(s, 1);
  s += __shfl_xor(s, 2);
  s += __shfl_xor(s, 4);
  const float u_ = s * (1.f / H);
  float s2 = 0.f;
#pragma unroll
  for (int i = 0; i < 16; ++i) { const float d = v[i] - u_; s2 += d * d; }
  s2 += __shfl_xor(s2, 1);
  s2 += __shfl_xor(s2, 2);
  s2 += __shfl_xor(s2, 4);
  const float rinv = rsqrtf(s2 * (1.f / H) + EPS);
#pragma unroll
  for (int g = 0; g < 4; ++g) {
    float4 o;
    const int col = ch * 16 + g * 4;
    o.x = lnw[col + 0] * ((v[g * 4 + 0] - u_) * rinv) + lnb[col + 0];
    o.y = lnw[col + 1] * ((v[g * 4 + 1] - u_) * rinv) + lnb[col + 1];
    o.z = lnw[col + 2] * ((v[g * 4 + 2] - u_) * rinv) + lnb[col + 2];
    o.w = lnw[col + 3] * ((v[g * 4 + 3] - u_) * rinv) + lnb[col + 3];
    *(float4*)&out[(r0 + rl) * H + col] = o;
  }
}

extern "C" void kernel_launch(void* const* d_in, const int* in_sizes, int n_in,
                              void* d_out, int out_size, void* d_ws, size_t ws_size,
                              hipStream_t stream) {
  const float* item = (const float*)d_in[0];
  const float* beh  = (const float*)d_in[1];
  const float* mask = (const float*)d_in[2];
  const float* Wq  = (const float*)d_in[3];  const float* bq  = (const float*)d_in[4];
  const float* Wk  = (const float*)d_in[5];  const float* bk  = (const float*)d_in[6];
  const float* Wv  = (const float*)d_in[7];  const float* bv  = (const float*)d_in[8];
  const float* Wqb = (const float*)d_in[9];  const float* bqb = (const float*)d_in[10];
  const float* Wkb = (const float*)d_in[11]; const float* bkb = (const float*)d_in[12];
  // d_in[13]/[14] = Wvb/bvb: dead code in the reference
  const float* Wf  = (const float*)d_in[15]; const float* bfv = (const float*)d_in[16];
  const float* lnw = (const float*)d_in[17]; const float* lnb = (const float*)d_in[18];
  float* out = (float*)d_out;

  ushort_t* ws = (ushort_t*)d_ws;
  ushort_t* Qw   = ws;
  ushort_t* Kw   = Qw + NE;
  ushort_t* Qbw  = Kw + NE;
  ushort_t* Kbw  = Qbw + NE;
  ushort_t* Vtw  = Kbw + NE;
  ushort_t* Attw = Vtw + NE;
  ushort_t* Wt   = Attw + NE;   // 6 * H*H bf16

  wcvt_kernel<<<dim3(4, 6), 256, 0, stream>>>(Wq, Wk, Wv, Wqb, Wkb, Wf, Wt);
  proj_kernel<<<dim3((B * S) / 32), 256, 0, stream>>>(
      item, beh, Wt, bq, bk, bv, bqb, bkb, Qw, Kw, Qbw, Kbw, Vtw);
  attn_kernel<<<dim3(S / QT, B), 256, 0, stream>>>(
      Qw, Kw, Qbw, Kbw, Vtw, mask, Attw);
  out_kernel<<<dim3((B * S) / 32), 256, 0, stream>>>(
      Attw, item, Wt + 5 * H * H, bfv, lnw, lnb, out);
}